// Round 11
// baseline (5189.608 us; speedup 1.0000x reference)
//
#include <hip/hip_runtime.h>
#include <cstddef>

#define HID   512
#define G4    2048   // 4*HID
#define NB    32     // batch
#define SEQL  1024
#define INPD  512
#define NBLK  128    // persistent blocks: block j owns hidden units [4j, 4j+4)
#define TPB   512

typedef _Float16 h2 __attribute__((ext_vector_type(2)));

#if __has_builtin(__builtin_amdgcn_fdot2)
__device__ __forceinline__ float FDOT2(h2 a, h2 b, float c) {
    return __builtin_amdgcn_fdot2(a, b, c, false);
}
#else
__device__ __forceinline__ float FDOT2(h2 a, h2 b, float c) {
    return fmaf((float)a[0], (float)b[0], fmaf((float)a[1], (float)b[1], c));
}
#endif

__device__ __forceinline__ float sigm(float x) {
    return 1.0f / (1.0f + __expf(-x));
}
__device__ __forceinline__ float tanh_fast(float x) {
    float e = __expf(-2.0f * fabsf(x));
    float t = (1.0f - e) / (1.0f + e);
    return copysignf(t, x);
}

// Permuted gate index: g' = j*16 + type*4 + uu  (block j's 16 gates contiguous)
__device__ __forceinline__ int orig_gate(int gp) {
    int r = gp & 15;
    return (r >> 2) * HID + (gp >> 4) * 4 + (r & 3);
}

// ---- one-time: W_hh fp32 [2048][512] -> fp16, per-block unit-major layout:
//      wh[j][p][k], p = uu*4 + type   (uu = unit-within-block, type = gate)
__global__ __launch_bounds__(256) void conv_whh(const float* __restrict__ whh,
                                                _Float16* __restrict__ wh) {
    int e = blockIdx.x * 256 + threadIdx.x;   // e < 2048*512
    int R = e >> 9, k = e & 511;
    int type = R >> 9, rem = R & 511;
    int j = rem >> 2, uu = rem & 3;
    int p = uu * 4 + type;
    wh[((size_t)j * 16 + p) * 512 + k] = (_Float16)whh[e];
}

// ---- one-time: h0 fp32 -> fp16 into hbuf buffer 0
__global__ __launch_bounds__(256) void conv_h0(const float* __restrict__ h0,
                                               _Float16* __restrict__ hb) {
    int e = blockIdx.x * 256 + threadIdx.x;   // e < NB*HID
    hb[e] = (_Float16)h0[e];
}

// x_proj chunk GEMM with PERMUTED output columns (unchanged from round 6)
__global__ __launch_bounds__(256) void xproj_gemm(const float* __restrict__ x,
                                                  const float* __restrict__ wih,
                                                  const float* __restrict__ bih,
                                                  const float* __restrict__ bhh,
                                                  float* __restrict__ xbuf,
                                                  int chunk, int SC) {
    __shared__ float As[16][68];
    __shared__ float Bs[16][68];
    const int m0 = blockIdx.x * 64;
    const int n0 = blockIdx.y * 64;
    const int tid = threadIdx.x;
    const int tx = tid % 16;
    const int ty = tid / 16;
    const int lr  = tid / 4;
    const int lc4 = tid % 4;

    float acc[4][4] = {};

    const int m = m0 + lr;
    const int b  = m / SC;
    const int tl = m % SC;
    const float* arow_base = x + ((size_t)b * SEQL + (size_t)chunk * SC + tl) * INPD + lc4 * 4;
    const float* brow_base = wih + (size_t)orig_gate(n0 + lr) * INPD + lc4 * 4;

    for (int k0 = 0; k0 < 512; k0 += 16) {
        float4 a4 = *(const float4*)(arow_base + k0);
        float4 b4 = *(const float4*)(brow_base + k0);
        As[lc4 * 4 + 0][lr] = a4.x;
        As[lc4 * 4 + 1][lr] = a4.y;
        As[lc4 * 4 + 2][lr] = a4.z;
        As[lc4 * 4 + 3][lr] = a4.w;
        Bs[lc4 * 4 + 0][lr] = b4.x;
        Bs[lc4 * 4 + 1][lr] = b4.y;
        Bs[lc4 * 4 + 2][lr] = b4.z;
        Bs[lc4 * 4 + 3][lr] = b4.w;
        __syncthreads();
        #pragma unroll
        for (int kk = 0; kk < 16; ++kk) {
            float4 av = *(const float4*)&As[kk][ty * 4];
            float4 bv = *(const float4*)&Bs[kk][tx * 4];
            float a[4] = {av.x, av.y, av.z, av.w};
            float bb[4] = {bv.x, bv.y, bv.z, bv.w};
            #pragma unroll
            for (int i = 0; i < 4; ++i)
                #pragma unroll
                for (int jj = 0; jj < 4; ++jj)
                    acc[i][jj] = fmaf(a[i], bb[jj], acc[i][jj]);
        }
        __syncthreads();
    }

    #pragma unroll
    for (int i = 0; i < 4; ++i) {
        int mo = m0 + ty * 4 + i;
        float* orow = xbuf + (size_t)mo * G4;
        #pragma unroll
        for (int jj = 0; jj < 4; ++jj) {
            int n = n0 + tx * 4 + jj;
            int og = orig_gate(n);
            orow[n] = acc[i][jj] + bih[og] + bhh[og];
        }
    }
}

// Persistent recurrence. 128 blocks x 512 threads; block j owns hidden units
// [4j,4j+4) => 16 gate rows x 32 batches.
// fp16 data path: W slice (16x512 fp16) lives in LDS (filled once/launch from
// the preconverted unit-major layout); h exchanged as fp16 through hbuf
// (LLC relaxed atomics) and staged to LDS; gate dot = v_dot2_f32_f16 with
// fp32 accumulate. Partials/cell/out/cstate stay fp32.
__global__ __launch_bounds__(512, 1)
void lstm_persist(const _Float16* __restrict__ wh,   // [NBLK][16][512] fp16
                  const float* __restrict__ xbuf,    // [NB*SC][G4] permuted
                  const float* __restrict__ c0,
                  unsigned long long* __restrict__ hbuf, // fp16 [2][NB][HID] as u64
                  float* __restrict__ cstate,        // [NB][HID]
                  float* __restrict__ out,           // [NB][SEQL][HID]
                  int* __restrict__ flags,           // [NBLK*32]
                  int step_base, int SC) {
    __shared__ _Float16 W_lds[16 * 520];   // row stride 520 halves (16B aligned)
    __shared__ _Float16 h_lds[32 * 520];
    __shared__ float    part[256 * 33];    // [kc*16+v][og]
    __shared__ float    gl[32 * 17];       // [b][r], r = type*4+uu

    const int j  = blockIdx.x;
    const int t  = threadIdx.x;
    const int u0 = 4 * j;

    // ---- compute-role indices
    const int kc = t >> 5;        // 0..15 : k-slice [32kc, 32kc+32)
    const int og = t & 31;
    const int b4 = og & 7;        // batches b4+8*db
    const int r4 = og >> 3;       // gate type

    // ---- reduce-role
    const int og_r = t & 31;
    const int v_r  = t >> 5;                          // 0..15
    const int r_r  = (og_r >> 3) * 4 + (v_r >> 2);    // local gate row
    const int b_r  = (og_r & 7) + 8 * (v_r & 3);      // batch

    // ---- fill W_lds from preconverted global (coalesced, conflict-free)
    {
        const uint4* src = (const uint4*)(wh + (size_t)j * 16 * 512);
        #pragma unroll
        for (int i = 0; i < 2; ++i) {
            int unit = t + 512 * i;            // 16B unit, 0..1023
            int p = unit >> 6, k16 = unit & 63;
            *(uint4*)&W_lds[p * 520 + k16 * 8] = src[unit];
        }
    }

    // ---- cell state: thread t<64 owns batch b = t&31, units u0+2pp, u0+2pp+1
    float cA = 0.0f, cB = 0.0f;
    const int b_c = t & 31, pp = t >> 5;   // valid when t<64
    if (t < 64) {
        const float* cs = (step_base == 0 ? c0 : cstate) + b_c * HID + u0 + 2 * pp;
        float2 cv = *(const float2*)cs;
        cA = cv.x; cB = cv.y;
    }

    for (int s = 0; s < SC; ++s) {
        const int g = step_base + s;

        // prefetch this lane's xg (coalesced: block j's 16 gates contiguous)
        float xg = xbuf[((size_t)b_r * SC + s) * G4 + 16 * j + r_r];

        // ---- stage h (32KB fp16) into LDS via LLC-coherent 8B loads
        const unsigned long long* hs8 = hbuf + (size_t)(g & 1) * 4096;
        #pragma unroll
        for (int i = 0; i < 4; ++i) {
            unsigned long long va = __hip_atomic_load(hs8 + i * 1024 + 2 * t,
                                                      __ATOMIC_RELAXED,
                                                      __HIP_MEMORY_SCOPE_AGENT);
            unsigned long long vb = __hip_atomic_load(hs8 + i * 1024 + 2 * t + 1,
                                                      __ATOMIC_RELAXED,
                                                      __HIP_MEMORY_SCOPE_AGENT);
            int j16 = i * 512 + t;                    // 16B unit index
            int brow = j16 >> 6, k16 = j16 & 63;
            uint4 v;
            __builtin_memcpy(&v.x, &va, 8);
            __builtin_memcpy(&v.z, &vb, 8);
            *(uint4*)&h_lds[brow * 520 + k16 * 8] = v;
        }
        __syncthreads();

        // ---- phase A: fp16 dot2, W + h from LDS (16+16 ds_read_b128)
        float acc[4][4] = {};
        const int kb = 32 * kc;   // halves
        #pragma unroll
        for (int kf = 0; kf < 4; ++kf) {
            uint4 hq[4], wq[4];
            #pragma unroll
            for (int db = 0; db < 4; ++db)
                hq[db] = *(const uint4*)&h_lds[(b4 + 8 * db) * 520 + kb + kf * 8];
            #pragma unroll
            for (int dr = 0; dr < 4; ++dr)
                wq[dr] = *(const uint4*)&W_lds[(dr * 4 + r4) * 520 + kb + kf * 8];
            #pragma unroll
            for (int dr = 0; dr < 4; ++dr) {
                h2 w0 = __builtin_bit_cast(h2, wq[dr].x);
                h2 w1 = __builtin_bit_cast(h2, wq[dr].y);
                h2 w2 = __builtin_bit_cast(h2, wq[dr].z);
                h2 w3 = __builtin_bit_cast(h2, wq[dr].w);
                #pragma unroll
                for (int db = 0; db < 4; ++db) {
                    acc[dr][db] = FDOT2(w0, __builtin_bit_cast(h2, hq[db].x), acc[dr][db]);
                    acc[dr][db] = FDOT2(w1, __builtin_bit_cast(h2, hq[db].y), acc[dr][db]);
                    acc[dr][db] = FDOT2(w2, __builtin_bit_cast(h2, hq[db].z), acc[dr][db]);
                    acc[dr][db] = FDOT2(w3, __builtin_bit_cast(h2, hq[db].w), acc[dr][db]);
                }
            }
        }
        // ---- write k-partials: v = dr*4+db (conflict-free, 2 lanes/bank)
        #pragma unroll
        for (int v = 0; v < 16; ++v)
            part[(kc * 16 + v) * 33 + og] = acc[v >> 2][v & 3];
        __syncthreads();

        // ---- reduce 16 partials + xg -> gl
        float sum = xg;
        #pragma unroll
        for (int q = 0; q < 16; ++q)
            sum += part[(q * 16 + v_r) * 33 + og_r];
        gl[b_r * 17 + r_r] = sum;
        __syncthreads();

        // ---- phase B: cell update, 2 units per thread (t<64), fp16 h publish
        float hA = 0.0f, hB = 0.0f;
        if (t < 64) {
            int la = 2 * pp;      // local unit of first element
            float i0 = sigm(gl[b_c * 17 + 0  + la]);
            float f0 = sigm(gl[b_c * 17 + 4  + la]);
            float g0 = tanh_fast(gl[b_c * 17 + 8  + la]);
            float o0 = sigm(gl[b_c * 17 + 12 + la]);
            cA = fmaf(f0, cA, i0 * g0);
            hA = o0 * tanh_fast(cA);
            float i1 = sigm(gl[b_c * 17 + 0  + la + 1]);
            float f1 = sigm(gl[b_c * 17 + 4  + la + 1]);
            float g1 = tanh_fast(gl[b_c * 17 + 8  + la + 1]);
            float o1 = sigm(gl[b_c * 17 + 12 + la + 1]);
            cB = fmaf(f1, cB, i1 * g1);
            hB = o1 * tanh_fast(cB);

            h2 hv;
            hv[0] = (_Float16)hA;
            hv[1] = (_Float16)hB;
            unsigned hu = __builtin_bit_cast(unsigned, hv);
            unsigned* hb32 = (unsigned*)hbuf;
            __hip_atomic_store(hb32 + (size_t)((g + 1) & 1) * 8192
                                    + b_c * 256 + (u0 >> 1) + pp,
                               hu, __ATOMIC_RELAXED, __HIP_MEMORY_SCOPE_AGENT);
        }
        __syncthreads();   // drains each wave's vmcnt => h stores acked at LLC

        // ---- arrive
        if (t == 0)
            __hip_atomic_store(&flags[j * 32], g + 1,
                               __ATOMIC_RELAXED, __HIP_MEMORY_SCOPE_AGENT);

        // ---- out store (fp32) AFTER arrive: HBM ack overlaps the poll
        if (t < 64) {
            float2 ov; ov.x = hA; ov.y = hB;
            *(float2*)&out[((size_t)b_c * SEQL + g) * HID + u0 + 2 * pp] = ov;
        }

        // ---- wait: thread t polls flag t
        if (t < NBLK) {
            while (__hip_atomic_load(&flags[t * 32], __ATOMIC_RELAXED,
                                     __HIP_MEMORY_SCOPE_AGENT) < g + 1)
                __builtin_amdgcn_s_sleep(1);
        }
        __syncthreads();
    }

    if (t < 64) {
        float2 cv; cv.x = cA; cv.y = cB;
        *(float2*)&cstate[b_c * HID + u0 + 2 * pp] = cv;
    }
}

__global__ __launch_bounds__(256) void finalize(const _Float16* __restrict__ hfin,
                                                const float* __restrict__ cs,
                                                float* __restrict__ out) {
    int i = blockIdx.x * blockDim.x + threadIdx.x;
    size_t base = (size_t)NB * SEQL * HID;
    if (i < NB * HID) {
        out[base + i] = (float)hfin[i];
        out[base + NB * HID + i] = cs[i];
    }
}

extern "C" void kernel_launch(void* const* d_in, const int* in_sizes, int n_in,
                              void* d_out, int out_size, void* d_ws, size_t ws_size,
                              hipStream_t stream) {
    const float* x   = (const float*)d_in[0];
    const float* h0  = (const float*)d_in[1];
    const float* c0  = (const float*)d_in[2];
    const float* wih = (const float*)d_in[3];
    const float* whh = (const float*)d_in[4];
    const float* bih = (const float*)d_in[5];
    const float* bhh = (const float*)d_in[6];
    float* out = (float*)d_out;

    char* ws = (char*)d_ws;
    int*       flags  = (int*)ws;                                  // 16 KB
    _Float16*  hbuf_h = (_Float16*)(ws + 16384);                   // 64 KB (2 bufs)
    float*     cstate = (float*)(ws + 16384 + 65536);              // 64 KB
    _Float16*  wh_h   = (_Float16*)(ws + 16384 + 65536 + 65536);   // 2 MB
    float*     xbuf   = (float*)(ws + 16384 + 65536 + 65536 + 2097152);

    size_t fixed = 16384 + 65536 + 65536 + 2097152;
    int SC = SEQL;
    while (SC > 64 && fixed + (size_t)NB * SC * G4 * sizeof(float) > ws_size) SC >>= 1;

    hipMemsetAsync(flags, 0, 16384, stream);
    conv_whh<<<(2048 * 512) / 256, 256, 0, stream>>>(whh, wh_h);
    conv_h0<<<(NB * HID) / 256, 256, 0, stream>>>(h0, hbuf_h);

    int nchunks = SEQL / SC;
    for (int ch = 0; ch < nchunks; ++ch) {
        dim3 grd(NB * SC / 64, G4 / 64);
        xproj_gemm<<<grd, 256, 0, stream>>>(x, wih, bih, bhh, xbuf, ch, SC);
        lstm_persist<<<NBLK, TPB, 0, stream>>>(wh_h, xbuf, c0,
                                               (unsigned long long*)hbuf_h,
                                               cstate, out, flags, ch * SC, SC);
    }

    // total steps = 1024 (even) -> final h parity is buffer 0
    finalize<<<(NB * HID + 255) / 256, 256, 0, stream>>>(hbuf_h, cstate, out);
}

// Round 12
// 4180.870 us; speedup vs baseline: 1.2413x; 1.2413x over previous
//
#include <hip/hip_runtime.h>
#include <cstddef>

#define HID   512
#define G4    2048   // 4*HID
#define NB    32     // batch
#define SEQL  1024
#define INPD  512
#define NBLK  128    // persistent blocks: block j owns hidden units [4j, 4j+4)
#define TPB   512

typedef _Float16 half8 __attribute__((ext_vector_type(8)));
typedef float    f32x4 __attribute__((ext_vector_type(4)));

__device__ __forceinline__ float sigm(float x) {
    return 1.0f / (1.0f + __expf(-x));
}
__device__ __forceinline__ float tanh_fast(float x) {
    float e = __expf(-2.0f * fabsf(x));
    float t = (1.0f - e) / (1.0f + e);
    return copysignf(t, x);
}

// Permuted gate index: g' = j*16 + type*4 + uu  (block j's 16 gates contiguous)
__device__ __forceinline__ int orig_gate(int gp) {
    int r = gp & 15;
    return (r >> 2) * HID + (gp >> 4) * 4 + (r & 3);
}

// ---- one-time: W_hh fp32 [2048][512] -> fp16, per-block unit-major layout:
//      wh[j][p][k], p = uu*4 + type   (uu = unit-within-block, type = gate)
__global__ __launch_bounds__(256) void conv_whh(const float* __restrict__ whh,
                                                _Float16* __restrict__ wh) {
    int e = blockIdx.x * 256 + threadIdx.x;   // e < 2048*512
    int R = e >> 9, k = e & 511;
    int type = R >> 9, rem = R & 511;
    int j = rem >> 2, uu = rem & 3;
    int p = uu * 4 + type;
    wh[((size_t)j * 16 + p) * 512 + k] = (_Float16)whh[e];
}

// ---- one-time: h0 fp32 -> fp16 into hbuf buffer 0
__global__ __launch_bounds__(256) void conv_h0(const float* __restrict__ h0,
                                               _Float16* __restrict__ hb) {
    int e = blockIdx.x * 256 + threadIdx.x;   // e < NB*HID
    hb[e] = (_Float16)h0[e];
}

// x_proj chunk GEMM with PERMUTED output columns (unchanged)
__global__ __launch_bounds__(256) void xproj_gemm(const float* __restrict__ x,
                                                  const float* __restrict__ wih,
                                                  const float* __restrict__ bih,
                                                  const float* __restrict__ bhh,
                                                  float* __restrict__ xbuf,
                                                  int chunk, int SC) {
    __shared__ float As[16][68];
    __shared__ float Bs[16][68];
    const int m0 = blockIdx.x * 64;
    const int n0 = blockIdx.y * 64;
    const int tid = threadIdx.x;
    const int tx = tid % 16;
    const int ty = tid / 16;
    const int lr  = tid / 4;
    const int lc4 = tid % 4;

    float acc[4][4] = {};

    const int m = m0 + lr;
    const int b  = m / SC;
    const int tl = m % SC;
    const float* arow_base = x + ((size_t)b * SEQL + (size_t)chunk * SC + tl) * INPD + lc4 * 4;
    const float* brow_base = wih + (size_t)orig_gate(n0 + lr) * INPD + lc4 * 4;

    for (int k0 = 0; k0 < 512; k0 += 16) {
        float4 a4 = *(const float4*)(arow_base + k0);
        float4 b4 = *(const float4*)(brow_base + k0);
        As[lc4 * 4 + 0][lr] = a4.x;
        As[lc4 * 4 + 1][lr] = a4.y;
        As[lc4 * 4 + 2][lr] = a4.z;
        As[lc4 * 4 + 3][lr] = a4.w;
        Bs[lc4 * 4 + 0][lr] = b4.x;
        Bs[lc4 * 4 + 1][lr] = b4.y;
        Bs[lc4 * 4 + 2][lr] = b4.z;
        Bs[lc4 * 4 + 3][lr] = b4.w;
        __syncthreads();
        #pragma unroll
        for (int kk = 0; kk < 16; ++kk) {
            float4 av = *(const float4*)&As[kk][ty * 4];
            float4 bv = *(const float4*)&Bs[kk][tx * 4];
            float a[4] = {av.x, av.y, av.z, av.w};
            float bb[4] = {bv.x, bv.y, bv.z, bv.w};
            #pragma unroll
            for (int i = 0; i < 4; ++i)
                #pragma unroll
                for (int jj = 0; jj < 4; ++jj)
                    acc[i][jj] = fmaf(a[i], bb[jj], acc[i][jj]);
        }
        __syncthreads();
    }

    #pragma unroll
    for (int i = 0; i < 4; ++i) {
        int mo = m0 + ty * 4 + i;
        float* orow = xbuf + (size_t)mo * G4;
        #pragma unroll
        for (int jj = 0; jj < 4; ++jj) {
            int n = n0 + tx * 4 + jj;
            int og = orig_gate(n);
            orow[n] = acc[i][jj] + bih[og] + bhh[og];
        }
    }
}

// Persistent recurrence, MFMA phase A.
// 128 blocks x 512 threads (8 waves); block j owns units [4j,4j+4).
// Per step: C[32b][16g] = h[32x512] * W^T[512x16] via mfma_f32_16x16x32_f16:
//   wave w: m-tile mt=w&1 (batches 16mt..16mt+15), k-steps kg*4..kg*4+3 (kg=w>>1)
//   -> 4 MFMA/wave, partial C (4 f32/lane) exchanged through LDS (8 KB),
//   reduced 4:1 by 512 threads, + xg -> gl -> cell update.
// A-frag: lane l reads h_lds[16mt+(l&15)][k + (l>>4)*8 .. +8)   (ds_read_b128)
// B-frag: lane l reads W_lds[l&15][k + (l>>4)*8 .. +8)
// D: col(gate)=lane&15, row(batch)=(lane>>4)*4+reg  [m89-verified]
__global__ __launch_bounds__(512, 1)
void lstm_persist(const _Float16* __restrict__ wh,   // [NBLK][16][512] fp16
                  const float* __restrict__ xbuf,    // [NB*SC][G4] permuted
                  const float* __restrict__ c0,
                  unsigned long long* __restrict__ hbuf, // fp16 [2][NB][HID] as u64
                  float* __restrict__ cstate,        // [NB][HID]
                  float* __restrict__ out,           // [NB][SEQL][HID]
                  int* __restrict__ flags,           // [NBLK*32]
                  int step_base, int SC) {
    __shared__ __align__(16) _Float16 W_lds[16 * 520];   // [p][k], stride 520 halves
    __shared__ __align__(16) _Float16 h_lds[32 * 520];   // [b][k]
    __shared__ __align__(16) float    part[8 * 264];     // [wave][lane*4+reg]
    __shared__ __align__(16) float    gl[32 * 20];       // [b][p]

    const int j  = blockIdx.x;
    const int t  = threadIdx.x;
    const int u0 = 4 * j;

    // ---- MFMA role
    const int w    = t >> 6, lane = t & 63;
    const int mt   = w & 1, kg = w >> 1;
    const int arow = 16 * mt + (lane & 15);   // batch row in h_lds
    const int brow = lane & 15;               // gate row p in W_lds
    const int kl   = (lane >> 4) * 8;         // k sub-offset

    // ---- reduce role: thread t -> output (batch b_t, gate n_r)
    const int mt_r = t & 1;
    const int idx  = t >> 1;
    const int n_r  = idx & 15;
    const int m_r  = idx >> 4;                            // 0..15
    const int b_t  = 16 * mt_r + m_r;
    const int src  = ((m_r >> 2) * 16 + n_r) * 4 + (m_r & 3);  // lane*4+reg
    const int xcol = 16 * j + (n_r & 3) * 4 + (n_r >> 2);      // p -> r permute

    // ---- fill W_lds from preconverted global (coalesced)
    {
        const uint4* srcp = (const uint4*)(wh + (size_t)j * 16 * 512);
        #pragma unroll
        for (int i = 0; i < 2; ++i) {
            int unit = t + 512 * i;            // 16B unit, 0..1023
            int p = unit >> 6, k16 = unit & 63;
            *(uint4*)&W_lds[p * 520 + k16 * 8] = srcp[unit];
        }
    }

    // ---- cell state: thread t<64 owns batch b_c = t&31, units u0+2pp, +1
    float cA = 0.0f, cB = 0.0f;
    const int b_c = t & 31, pp = t >> 5;   // valid when t<64
    if (t < 64) {
        const float* cs = (step_base == 0 ? c0 : cstate) + b_c * HID + u0 + 2 * pp;
        float2 cv = *(const float2*)cs;
        cA = cv.x; cB = cv.y;
    }

    for (int s = 0; s < SC; ++s) {
        const int g = step_base + s;

        // prefetch this lane's xg
        float xg = xbuf[((size_t)b_t * SC + s) * G4 + xcol];

        // ---- stage h (32KB fp16) into LDS via LLC-coherent 8B loads
        const unsigned long long* hs8 = hbuf + (size_t)(g & 1) * 4096;
        #pragma unroll
        for (int i = 0; i < 4; ++i) {
            unsigned long long va = __hip_atomic_load(hs8 + i * 1024 + 2 * t,
                                                      __ATOMIC_RELAXED,
                                                      __HIP_MEMORY_SCOPE_AGENT);
            unsigned long long vb = __hip_atomic_load(hs8 + i * 1024 + 2 * t + 1,
                                                      __ATOMIC_RELAXED,
                                                      __HIP_MEMORY_SCOPE_AGENT);
            int j16 = i * 512 + t;                    // 16B unit index
            int br = j16 >> 6, k16 = j16 & 63;
            uint4 v;
            __builtin_memcpy(&v.x, &va, 8);
            __builtin_memcpy(&v.z, &vb, 8);
            *(uint4*)&h_lds[br * 520 + k16 * 8] = v;
        }
        __syncthreads();

        // ---- phase A: 4 MFMA per wave
        f32x4 acc = {0.f, 0.f, 0.f, 0.f};
        #pragma unroll
        for (int q = 0; q < 4; ++q) {
            const int k = (kg * 4 + q) * 32 + kl;
            half8 av = *(const half8*)&h_lds[arow * 520 + k];
            half8 bv = *(const half8*)&W_lds[brow * 520 + k];
            acc = __builtin_amdgcn_mfma_f32_16x16x32_f16(av, bv, acc, 0, 0, 0);
        }
        *(f32x4*)&part[w * 264 + lane * 4] = acc;
        __syncthreads();

        // ---- reduce 4 k-group partials + xg -> gl[b][p]
        float sum = xg;
        #pragma unroll
        for (int kgg = 0; kgg < 4; ++kgg)
            sum += part[(kgg * 2 + mt_r) * 264 + src];
        gl[b_t * 20 + n_r] = sum;
        __syncthreads();

        // ---- phase B: cell update, 2 units per thread (t<64)
        float hA = 0.0f, hB = 0.0f;
        if (t < 64) {
            float4 gA = *(const float4*)&gl[b_c * 20 + 8 * pp];
            float4 gB = *(const float4*)&gl[b_c * 20 + 8 * pp + 4];
            cA = fmaf(sigm(gA.y), cA, sigm(gA.x) * tanh_fast(gA.z));
            hA = sigm(gA.w) * tanh_fast(cA);
            cB = fmaf(sigm(gB.y), cB, sigm(gB.x) * tanh_fast(gB.z));
            hB = sigm(gB.w) * tanh_fast(cB);

            _Float16 hv2[2] = {(_Float16)hA, (_Float16)hB};
            unsigned hu;
            __builtin_memcpy(&hu, hv2, 4);
            unsigned* hb32 = (unsigned*)hbuf;
            __hip_atomic_store(hb32 + (size_t)((g + 1) & 1) * 8192
                                    + b_c * 256 + (u0 >> 1) + pp,
                               hu, __ATOMIC_RELAXED, __HIP_MEMORY_SCOPE_AGENT);
        }
        __syncthreads();   // drains each wave's vmcnt => h stores acked at LLC

        // ---- arrive
        if (t == 0)
            __hip_atomic_store(&flags[j * 32], g + 1,
                               __ATOMIC_RELAXED, __HIP_MEMORY_SCOPE_AGENT);

        // ---- out store (fp32) AFTER arrive: HBM ack overlaps the poll
        if (t < 64) {
            float2 ov; ov.x = hA; ov.y = hB;
            *(float2*)&out[((size_t)b_c * SEQL + g) * HID + u0 + 2 * pp] = ov;
        }

        // ---- wait: thread t polls flag t
        if (t < NBLK) {
            while (__hip_atomic_load(&flags[t * 32], __ATOMIC_RELAXED,
                                     __HIP_MEMORY_SCOPE_AGENT) < g + 1)
                __builtin_amdgcn_s_sleep(1);
        }
        __syncthreads();
    }

    if (t < 64) {
        float2 cv; cv.x = cA; cv.y = cB;
        *(float2*)&cstate[b_c * HID + u0 + 2 * pp] = cv;
    }
}

__global__ __launch_bounds__(256) void finalize(const _Float16* __restrict__ hfin,
                                                const float* __restrict__ cs,
                                                float* __restrict__ out) {
    int i = blockIdx.x * blockDim.x + threadIdx.x;
    size_t base = (size_t)NB * SEQL * HID;
    if (i < NB * HID) {
        out[base + i] = (float)hfin[i];
        out[base + NB * HID + i] = cs[i];
    }
}

extern "C" void kernel_launch(void* const* d_in, const int* in_sizes, int n_in,
                              void* d_out, int out_size, void* d_ws, size_t ws_size,
                              hipStream_t stream) {
    const float* x   = (const float*)d_in[0];
    const float* h0  = (const float*)d_in[1];
    const float* c0  = (const float*)d_in[2];
    const float* wih = (const float*)d_in[3];
    const float* whh = (const float*)d_in[4];
    const float* bih = (const float*)d_in[5];
    const float* bhh = (const float*)d_in[6];
    float* out = (float*)d_out;

    char* ws = (char*)d_ws;
    int*       flags  = (int*)ws;                                  // 16 KB
    _Float16*  hbuf_h = (_Float16*)(ws + 16384);                   // 64 KB (2 bufs)
    float*     cstate = (float*)(ws + 16384 + 65536);              // 64 KB
    _Float16*  wh_h   = (_Float16*)(ws + 16384 + 65536 + 65536);   // 2 MB
    float*     xbuf   = (float*)(ws + 16384 + 65536 + 65536 + 2097152);

    size_t fixed = 16384 + 65536 + 65536 + 2097152;
    int SC = SEQL;
    while (SC > 64 && fixed + (size_t)NB * SC * G4 * sizeof(float) > ws_size) SC >>= 1;

    hipMemsetAsync(flags, 0, 16384, stream);
    conv_whh<<<(2048 * 512) / 256, 256, 0, stream>>>(whh, wh_h);
    conv_h0<<<(NB * HID) / 256, 256, 0, stream>>>(h0, hbuf_h);

    int nchunks = SEQL / SC;
    for (int ch = 0; ch < nchunks; ++ch) {
        dim3 grd(NB * SC / 64, G4 / 64);
        xproj_gemm<<<grd, 256, 0, stream>>>(x, wih, bih, bhh, xbuf, ch, SC);
        lstm_persist<<<NBLK, TPB, 0, stream>>>(wh_h, xbuf, c0,
                                               (unsigned long long*)hbuf_h,
                                               cstate, out, flags, ch * SC, SC);
    }

    // total steps = 1024 (even) -> final h parity is buffer 0
    finalize<<<(NB * HID + 255) / 256, 256, 0, stream>>>(hbuf_h, cstate, out);
}